// Round 13
// baseline (91.522 us; speedup 1.0000x reference)
//
#include <hip/hip_runtime.h>

typedef _Float16 half8_t __attribute__((ext_vector_type(8)));
typedef _Float16 half4_t __attribute__((ext_vector_type(4)));
typedef _Float16 half2_t __attribute__((ext_vector_type(2)));
typedef __fp16 fp16x2 __attribute__((ext_vector_type(2)));  // cvt_pkrtz return type
typedef float f32x4 __attribute__((ext_vector_type(4)));

static constexpr int SEQ = 2048;
static constexpr int DEMB = 1024;

// SESSION RULES:
//  (r5) no min-waves __launch_bounds__ hints — flipped a passing build to absmax 1.15.
//  (r6) no hand-synchronized LDS staging; LDS only via __syncthreads(); cross-lane
//       movement via bpermute/shfl intrinsics.
//  (r8) per-wave ILP via source prefetch gets legally re-serialized by the
//       compiler. Hide latency structurally: LDS staging + waves.
//  (r9) equalize work per BLOCK (complementary q-tile pairs).
//  (r10/r11) >=2 phases of staging slack is enough; deeper is neutral.
//  (r12) more waves per BLOCK is NEGATIVE (wider barrier + duplicated W loads).
//        Scale with independent blocks/CU instead.

__device__ __forceinline__ float fexp2(float x) {
#if __has_builtin(__builtin_amdgcn_exp2f)
  return __builtin_amdgcn_exp2f(x);
#else
  return exp2f(x);
#endif
}

__device__ __forceinline__ half8_t cvt8(float4 a, float4 b) {
  half8_t xf;
  xf[0] = (_Float16)a.x; xf[1] = (_Float16)a.y;
  xf[2] = (_Float16)a.z; xf[3] = (_Float16)a.w;
  xf[4] = (_Float16)b.x; xf[5] = (_Float16)b.y;
  xf[6] = (_Float16)b.z; xf[7] = (_Float16)b.w;
  return xf;
}

// ---------------- kernel 1: W -> Wt fp16 [192][1024] ----------------
__global__ __launch_bounds__(256) void wt_kernel(const float* __restrict__ Wq,
                                                 const float* __restrict__ Wk,
                                                 const float* __restrict__ Wv,
                                                 _Float16* __restrict__ Wt) {
  int i = blockIdx.x * 256 + threadIdx.x;  // [0, 196608)
  int n = i >> 10;
  int k = i & 1023;
  const float* W = (n < 64) ? Wq : ((n < 128) ? Wk : Wv);
  Wt[i] = (_Float16)W[k * 64 + (n & 63)];
}

// ---------------- kernel 2: QKV projection, LDS-staged GEMM, 4 blocks/CU ----------------
// Block = 256 threads = 4 waves, M-tile = 16 x-rows, grid 1024 -> 4 independent
// blocks/CU (r12 showed waves-per-block scaling is negative; independent
// barriers interleave). 16 K-chunks of 64. Per chunk the 4 KB x-tile (16x64
// f32, XOR-swizzled) is staged once (one float4/thread, 2 chunks of slack).
// Wave wv owns 3 distinct n-tiles (no W duplication); 6 MFMA/chunk/wave.
__global__ __launch_bounds__(256) void proj_kernel(const float* __restrict__ x,
                                                   const _Float16* __restrict__ Wt,
                                                   _Float16* __restrict__ Qh,
                                                   _Float16* __restrict__ Kh,
                                                   _Float16* __restrict__ Vt) {
  __shared__ __align__(16) char sbuf[8192];  // 2 x 4 KB x-tile (f32, swizzled)

  const int tid = threadIdx.x;
  const int lane = tid & 63;
  const int nw = tid >> 6;        // wave = n-group 0..3
  const int g = lane >> 4;        // 0..3
  const int c = lane & 15;        // 0..15
  const int m0 = blockIdx.x * 16;

  // staging: thread owns row srow = tid>>4, 16B piece pc = tid&15 (row = 256 B)
  const int srow = tid >> 4;
  const int pc = tid & 15;
  const float* xsrc = x + (size_t)(m0 + srow) * DEMB + pc * 4;
  char* lws = sbuf + ((unsigned)(srow * 256 + pc * 16) ^ (unsigned)((srow & 7) << 4));

  // read side: row = c -> swizzle key (c&7); k-step ks: byte base =
  // c*256 + ks*128 + g*32, two float4s (base, base+16)
  const unsigned sw = (unsigned)((c & 7) << 4);
  const unsigned rbase = (unsigned)(c * 256 + g * 32);

  const f32x4 zero = {0.f, 0.f, 0.f, 0.f};
  f32x4 acc[3];
#pragma unroll
  for (int j = 0; j < 3; ++j) acc[j] = zero;

  const _Float16* wb0 = Wt + (size_t)((3 * nw + 0) * 16 + c) * 1024 + 8 * g;
  const _Float16* wb1 = Wt + (size_t)((3 * nw + 1) * 16 + c) * 1024 + 8 * g;
  const _Float16* wb2 = Wt + (size_t)((3 * nw + 2) * 16 + c) * 1024 + 8 * g;
  half8_t wfA0 = *(const half8_t*)(wb0);
  half8_t wfA1 = *(const half8_t*)(wb1);
  half8_t wfA2 = *(const half8_t*)(wb2);
  half8_t wfB0 = *(const half8_t*)(wb0 + 32);
  half8_t wfB1 = *(const half8_t*)(wb1 + 32);
  half8_t wfB2 = *(const half8_t*)(wb2 + 32);

  // prologue: stage chunk 0; hold chunk 1 pending in a register
  {
    float4 s0 = *(const float4*)(xsrc);
    *(float4*)(lws) = s0;
  }
  float4 p0 = *(const float4*)(xsrc + 64);
  __syncthreads();

  for (int t = 0; t < 16; ++t) {
    // issue chunk t+2 x-load (written at end of iter t+1)
    float4 q0 = {0.f, 0.f, 0.f, 0.f};
    if (t < 14) q0 = *(const float4*)(xsrc + (t + 2) * 64);
    // issue W fragments for chunk t+1
    half8_t wnA0{}, wnA1{}, wnA2{}, wnB0{}, wnB1{}, wnB2{};
    if (t < 15) {
      const int kc = (t + 1) * 64;
      wnA0 = *(const half8_t*)(wb0 + kc);
      wnA1 = *(const half8_t*)(wb1 + kc);
      wnA2 = *(const half8_t*)(wb2 + kc);
      wnB0 = *(const half8_t*)(wb0 + kc + 32);
      wnB1 = *(const half8_t*)(wb1 + kc + 32);
      wnB2 = *(const half8_t*)(wb2 + kc + 32);
    }
    // compute chunk t from buf[t&1]: 2 k-steps x 3 n-tiles
    const char* rb = sbuf + (t & 1) * 4096;
    half8_t xfA = cvt8(*(const float4*)(rb + (rbase ^ sw)),
                       *(const float4*)(rb + ((rbase + 16) ^ sw)));
    half8_t xfB = cvt8(*(const float4*)(rb + ((rbase + 128) ^ sw)),
                       *(const float4*)(rb + ((rbase + 144) ^ sw)));
#pragma unroll
    for (int j = 0; j < 3; ++j) {
      half8_t wA = (j == 0) ? wfA0 : ((j == 1) ? wfA1 : wfA2);
      half8_t wB = (j == 0) ? wfB0 : ((j == 1) ? wfB1 : wfB2);
      const int nt = 3 * nw + j;
      if (nt < 8) {  // Q/K: swapped -> D[n][m]
        acc[j] = __builtin_amdgcn_mfma_f32_16x16x32_f16(wA, xfA, acc[j], 0, 0, 0);
        acc[j] = __builtin_amdgcn_mfma_f32_16x16x32_f16(wB, xfB, acc[j], 0, 0, 0);
      } else {       // V: normal -> D[m][n]
        acc[j] = __builtin_amdgcn_mfma_f32_16x16x32_f16(xfA, wA, acc[j], 0, 0, 0);
        acc[j] = __builtin_amdgcn_mfma_f32_16x16x32_f16(xfB, wB, acc[j], 0, 0, 0);
      }
    }
    // stage chunk t+1 (pending since iter t-1 -> ~2 compute phases of slack)
    if (t < 15) *(float4*)(lws + ((t + 1) & 1) * 4096) = p0;
    __syncthreads();
    p0 = q0;
    wfA0 = wnA0; wfA1 = wnA1; wfA2 = wnA2;
    wfB0 = wnB0; wfB1 = wnB1; wfB2 = wnB2;
  }

  // ---- stores: wave owns n-tiles 3nw..3nw+2 of the 16-row m-tile ----
  const int b = m0 >> 11;
#pragma unroll
  for (int j = 0; j < 3; ++j) {
    const int nt = 3 * nw + j;
    half4_t h;
    h[0] = (_Float16)acc[j][0]; h[1] = (_Float16)acc[j][1];
    h[2] = (_Float16)acc[j][2]; h[3] = (_Float16)acc[j][3];
    if (nt < 4) {        // Q: D[n][m]: row m0+c, col nt*16+4g+r
      *(half4_t*)(Qh + (size_t)(m0 + c) * 64 + nt * 16 + 4 * g) = h;
    } else if (nt < 8) { // K
      *(half4_t*)(Kh + (size_t)(m0 + c) * 64 + (nt - 4) * 16 + 4 * g) = h;
    } else {             // V: D[s][h] -> Vt[b][h][s]
      const int hh = (nt - 8) * 16 + c;
      const int s0 = (m0 & 2047) + 4 * g;
      *(half4_t*)(Vt + (size_t)(b * 64 + hh) * 2048 + s0) = h;
    }
  }
}

// ---------------- attn helpers (verbatim r10/r11 passing) ----------------
__device__ __forceinline__ void flash_tile(int q0, int wv, int g, int c,
                                           const _Float16* __restrict__ Qb,
                                           const _Float16* __restrict__ Kb,
                                           const _Float16* __restrict__ Vb,
                                           f32x4 (&acc)[4], float& m2, float& lsum) {
  const f32x4 zero = {0.f, 0.f, 0.f, 0.f};
  const float CS = 0.18033688011112042f;  // 0.125 * log2(e)
  const int q_lane = q0 + c;
  const int nb = ((q0 + 15) >> 6) + 1;

  const _Float16* Qrow = Qb + (size_t)(q0 + c) * 64;
  half8_t qf0 = *(const half8_t*)(Qrow + 8 * g);
  half8_t qf1 = *(const half8_t*)(Qrow + 32 + 8 * g);

  const int addr_u01 = (2 * (g & 1)) * 64 + c * 4;
  const int addr_u23 = (2 * (g & 1) + 1) * 64 + c * 4;
  const bool glo = (g < 2);

  for (int jb = wv; jb < nb; jb += 8) {
    const int k0 = jb * 64;
    f32x4 sacc[4];
#pragma unroll
    for (int kt = 0; kt < 4; ++kt) {
      const _Float16* Krow = Kb + (size_t)(k0 + kt * 16 + c) * 64;
      half8_t kf0 = *(const half8_t*)(Krow + 8 * g);
      half8_t kf1 = *(const half8_t*)(Krow + 32 + 8 * g);
      f32x4 t = zero;
      t = __builtin_amdgcn_mfma_f32_16x16x32_f16(kf0, qf0, t, 0, 0, 0);
      t = __builtin_amdgcn_mfma_f32_16x16x32_f16(kf1, qf1, t, 0, 0, 0);
      sacc[kt] = t;
    }
    half8_t vf0[4], vf1[4];
#pragma unroll
    for (int ht = 0; ht < 4; ++ht) {
      const _Float16* Vrow = Vb + (size_t)(16 * ht + c) * 2048 + k0;
      vf0[ht] = *(const half8_t*)(Vrow + 8 * g);
      vf1[ht] = *(const half8_t*)(Vrow + 32 + 8 * g);
    }
    const bool full = (k0 + 63 <= q0);
    float pv[16];
    float bmax = -3.0e38f;
#pragma unroll
    for (int kt = 0; kt < 4; ++kt) {
#pragma unroll
      for (int r = 0; r < 4; ++r) {
        float sv = sacc[kt][r] * CS;
        if (!full) {
          int kidx = k0 + kt * 16 + 4 * g + r;
          sv = (kidx > q_lane) ? -3.0e38f : sv;
        }
        pv[kt * 4 + r] = sv;
        bmax = fmaxf(bmax, sv);
      }
    }
    bmax = fmaxf(bmax, __shfl_xor(bmax, 16));
    bmax = fmaxf(bmax, __shfl_xor(bmax, 32));
    const float mnew = fmaxf(m2, bmax);
    const float fsc = fexp2(m2 - mnew);
    m2 = mnew;
    float psum = 0.f;
#pragma unroll
    for (int t = 0; t < 16; ++t) {
      pv[t] = fexp2(pv[t] - m2);
      psum += pv[t];
    }
    lsum = lsum * fsc + psum;
#pragma unroll
    for (int ht = 0; ht < 4; ++ht) {
#pragma unroll
      for (int r = 0; r < 4; ++r) acc[ht][r] *= fsc;
    }
    int h2[8];
#pragma unroll
    for (int kt = 0; kt < 4; ++kt) {
#pragma unroll
      for (int bb = 0; bb < 2; ++bb) {
        fp16x2 hv = __builtin_amdgcn_cvt_pkrtz(pv[kt * 4 + 2 * bb],
                                               pv[kt * 4 + 2 * bb + 1]);
        h2[kt * 2 + bb] = __builtin_bit_cast(int, hv);
      }
    }
    half8_t pf0, pf1;
#pragma unroll
    for (int u = 0; u < 4; ++u) {
      const int addr = (u < 2) ? addr_u01 : addr_u23;
#pragma unroll
      for (int h = 0; h < 2; ++h) {
        int r1 = __builtin_amdgcn_ds_bpermute(addr, h2[4 * h + (u & 1)]);
        int r2 = __builtin_amdgcn_ds_bpermute(addr, h2[4 * h + 2 + (u & 1)]);
        half2_t t = __builtin_bit_cast(half2_t, glo ? r1 : r2);
        if (h == 0) { pf0[2 * u] = t[0]; pf0[2 * u + 1] = t[1]; }
        else        { pf1[2 * u] = t[0]; pf1[2 * u + 1] = t[1]; }
      }
    }
#pragma unroll
    for (int ht = 0; ht < 4; ++ht) {
      acc[ht] = __builtin_amdgcn_mfma_f32_16x16x32_f16(vf0[ht], pf0, acc[ht], 0, 0, 0);
      acc[ht] = __builtin_amdgcn_mfma_f32_16x16x32_f16(vf1[ht], pf1, acc[ht], 0, 0, 0);
    }
  }
}

__device__ __forceinline__ void combine_tile(char* shraw, int tid, int wv, int g, int c,
                                             int b, int q0, f32x4 (&acc)[4],
                                             float m2, float lsum,
                                             float* __restrict__ out) {
  float* Mm = (float*)(shraw + 34816);
  float* Ll = (float*)(shraw + 35328);
  lsum += __shfl_xor(lsum, 16);
  lsum += __shfl_xor(lsum, 32);
  Mm[wv * 16 + c] = m2;
  Ll[wv * 16 + c] = lsum;
  float* OmW = (float*)shraw + wv * 1088 + c * 68;
#pragma unroll
  for (int ht = 0; ht < 4; ++ht) {
    *(f32x4*)(OmW + ht * 16 + 4 * g) = acc[ht];
  }
  __syncthreads();
  const int r = tid & 15;
  const int cp = tid >> 4;  // 0..31
  const float* OmF = (const float*)shraw;
  float mf = Mm[r];
#pragma unroll
  for (int i = 1; i < 8; ++i) mf = fmaxf(mf, Mm[i * 16 + r]);
  float lf = 0.f, o0 = 0.f, o1 = 0.f;
#pragma unroll
  for (int i = 0; i < 8; ++i) {
    float sc = fexp2(Mm[i * 16 + r] - mf);
    lf += Ll[i * 16 + r] * sc;
    const float* p = OmF + i * 1088 + r * 68 + 2 * cp;
    o0 += p[0] * sc;
    o1 += p[1] * sc;
  }
  const float inv = 1.0f / lf;
  float2 o;
  o.x = o0 * inv;
  o.y = o1 * inv;
  *(float2*)(out + (size_t)(b * 2048 + q0 + r) * 64 + 2 * cp) = o;
}

// ---------------- kernel 3: causal flash attention, paired q-tiles ----------------
__global__ __launch_bounds__(512) void attn_kernel(const _Float16* __restrict__ Qh,
                                                   const _Float16* __restrict__ Kh,
                                                   const _Float16* __restrict__ Vt,
                                                   float* __restrict__ out) {
  __shared__ __align__(16) char shraw[35840];

  const int tid = threadIdx.x;
  const int lane = tid & 63;
  const int wv = tid >> 6;       // 0..7
  const int g = lane >> 4;
  const int c = lane & 15;
  const int pr = blockIdx.x & 63;   // pair index 0..63
  const int b = blockIdx.x >> 6;
  const int q0A = pr * 16;              // small tile
  const int q0B = (127 - pr) * 16;      // large tile

  const _Float16* Qb = Qh + (size_t)b * 2048 * 64;
  const _Float16* Kb = Kh + (size_t)b * 2048 * 64;
  const _Float16* Vb = Vt + (size_t)b * 64 * 2048;

  const f32x4 zero = {0.f, 0.f, 0.f, 0.f};
  f32x4 accA[4], accB[4];
#pragma unroll
  for (int t = 0; t < 4; ++t) { accA[t] = zero; accB[t] = zero; }
  float mA = -3.0e38f, lA = 0.f;
  float mB = -3.0e38f, lB = 0.f;

  flash_tile(q0A, wv, g, c, Qb, Kb, Vb, accA, mA, lA);
  flash_tile(q0B, wv, g, c, Qb, Kb, Vb, accB, mB, lB);

  combine_tile(shraw, tid, wv, g, c, b, q0A, accA, mA, lA, out);
  __syncthreads();  // A's Om reads done before B overwrites
  combine_tile(shraw, tid, wv, g, c, b, q0B, accB, mB, lB, out);
}

extern "C" void kernel_launch(void* const* d_in, const int* in_sizes, int n_in,
                              void* d_out, int out_size, void* d_ws, size_t ws_size,
                              hipStream_t stream) {
  const float* x  = (const float*)d_in[0];
  const float* Wq = (const float*)d_in[1];
  const float* Wk = (const float*)d_in[2];
  const float* Wv = (const float*)d_in[3];
  char* ws = (char*)d_ws;
  _Float16* Wt = (_Float16*)(ws);                // 192*1024*2      = 393216 B
  _Float16* Qh = (_Float16*)(ws + 393216);       // 16384*64*2      = 2097152 B
  _Float16* Kh = (_Float16*)(ws + 2490368);      // 16384*64*2
  _Float16* Vt = (_Float16*)(ws + 4587520);      // 8*64*2048*2
  float* out = (float*)d_out;

  wt_kernel<<<dim3(768), dim3(256), 0, stream>>>(Wq, Wk, Wv, Wt);
  proj_kernel<<<dim3(1024), dim3(256), 0, stream>>>(x, Wt, Qh, Kh, Vt);
  attn_kernel<<<dim3(512), dim3(512), 0, stream>>>(Qh, Kh, Vt, out);
}

// Round 14
// 70.753 us; speedup vs baseline: 1.2935x; 1.2935x over previous
//
#include <hip/hip_runtime.h>

typedef _Float16 half8_t __attribute__((ext_vector_type(8)));
typedef _Float16 half4_t __attribute__((ext_vector_type(4)));
typedef _Float16 half2_t __attribute__((ext_vector_type(2)));
typedef __fp16 fp16x2 __attribute__((ext_vector_type(2)));  // cvt_pkrtz return type
typedef float f32x4 __attribute__((ext_vector_type(4)));

static constexpr int SEQ = 2048;
static constexpr int DEMB = 1024;

// SESSION RULES:
//  (r5) no min-waves __launch_bounds__ hints — flipped a passing build to absmax 1.15.
//  (r6) no hand-synchronized LDS staging; LDS only via __syncthreads(); cross-lane
//       movement via bpermute/shfl intrinsics.
//  (r8) per-wave ILP via source prefetch gets legally re-serialized by the
//       compiler. Hide latency structurally: LDS staging + waves.
//  (r9) equalize work per BLOCK (complementary q-tile pairs).
//  (r12/r13) neither more waves/block nor more blocks/CU helps proj.
//  (r14) MEASURED proj ranking: r9 (BK32, 1-slack, 48 VGPR) 29us << r10/r11
//        (BK64, 2-deep, 60 VGPR) 44us << r12/r13 53-55us. Small in-flight
//        footprint + small phase wins; r10's "deeper pipeline" was a regression
//        hidden by attn's simultaneous improvement. This file = r9 proj exactly.

__device__ __forceinline__ float fexp2(float x) {
#if __has_builtin(__builtin_amdgcn_exp2f)
  return __builtin_amdgcn_exp2f(x);
#else
  return exp2f(x);
#endif
}

__device__ __forceinline__ half8_t cvt8(float4 a, float4 b) {
  half8_t xf;
  xf[0] = (_Float16)a.x; xf[1] = (_Float16)a.y;
  xf[2] = (_Float16)a.z; xf[3] = (_Float16)a.w;
  xf[4] = (_Float16)b.x; xf[5] = (_Float16)b.y;
  xf[6] = (_Float16)b.z; xf[7] = (_Float16)b.w;
  return xf;
}

// ---------------- kernel 1: W -> Wt fp16 [192][1024] ----------------
__global__ __launch_bounds__(256) void wt_kernel(const float* __restrict__ Wq,
                                                 const float* __restrict__ Wk,
                                                 const float* __restrict__ Wv,
                                                 _Float16* __restrict__ Wt) {
  int i = blockIdx.x * 256 + threadIdx.x;  // [0, 196608)
  int n = i >> 10;
  int k = i & 1023;
  const float* W = (n < 64) ? Wq : ((n < 128) ? Wk : Wv);
  Wt[i] = (_Float16)W[k * 64 + (n & 63)];
}

// ---------------- kernel 2: QKV projection, LDS-staged GEMM (r9 verbatim) ----------------
// Block = 256 threads = 4 waves, M-tile = 32 rows, grid 512 (2 blocks/CU).
// 32 K-chunks of 32. Per chunk the 4 KB x-tile (32x32 f32, XOR-swizzled) is
// staged once (one float4/thread, 1 iteration of slack). Wave wv owns 3
// distinct n-tiles x 2 m-slices -> 6 MFMA/chunk/wave. Measured ~29 us.
__global__ __launch_bounds__(256) void proj_kernel(const float* __restrict__ x,
                                                   const _Float16* __restrict__ Wt,
                                                   _Float16* __restrict__ Qh,
                                                   _Float16* __restrict__ Kh,
                                                   _Float16* __restrict__ Vt) {
  __shared__ __align__(16) char sbuf[8192];  // 2 x 4 KB x-tile (f32, swizzled)

  const int tid = threadIdx.x;
  const int lane = tid & 63;
  const int wv = tid >> 6;        // 0..3
  const int g = lane >> 4;        // 0..3
  const int c = lane & 15;        // 0..15
  const int m0 = blockIdx.x * 32;

  // staging: thread tid owns tile row srow = tid>>3, 16 B at col (tid&7)*16B
  const int srow = tid >> 3;
  const float* xsrc = x + (size_t)(m0 + srow) * DEMB + (tid & 7) * 4;
  char* lws = sbuf + ((unsigned)(tid * 16) ^ (unsigned)((srow & 7) << 4));

  // read addresses: row = ms*16 + c, cols 8g.. (f32); swizzle by (row&7)=(c&7)
  const unsigned sw = (unsigned)((c & 7) << 4);
  const unsigned rA = (unsigned)(c * 128 + g * 32);

  const f32x4 zero = {0.f, 0.f, 0.f, 0.f};
  f32x4 acc[2][3];
#pragma unroll
  for (int ms = 0; ms < 2; ++ms)
#pragma unroll
    for (int j = 0; j < 3; ++j) acc[ms][j] = zero;

  const _Float16* wb0 = Wt + (size_t)((3 * wv + 0) * 16 + c) * 1024 + 8 * g;
  const _Float16* wb1 = Wt + (size_t)((3 * wv + 1) * 16 + c) * 1024 + 8 * g;
  const _Float16* wb2 = Wt + (size_t)((3 * wv + 2) * 16 + c) * 1024 + 8 * g;
  half8_t wf0 = *(const half8_t*)(wb0);
  half8_t wf1 = *(const half8_t*)(wb1);
  half8_t wf2 = *(const half8_t*)(wb2);

  // prologue: stage k-step 0
  {
    float4 xa = *(const float4*)(xsrc);
    *(float4*)(lws) = xa;
  }
  __syncthreads();

  for (int t = 0; t < 31; ++t) {
    const int kc = (t + 1) * 32;
    // issue next-step loads early (consumed at iter end / next iter)
    float4 xn = *(const float4*)(xsrc + kc);
    half8_t wn0 = *(const half8_t*)(wb0 + kc);
    half8_t wn1 = *(const half8_t*)(wb1 + kc);
    half8_t wn2 = *(const half8_t*)(wb2 + kc);
    // compute step t from buf[t&1]
    const char* rb = sbuf + (t & 1) * 4096;
    half8_t xf[2];
#pragma unroll
    for (int ms = 0; ms < 2; ++ms) {
      const unsigned base = rA + (unsigned)(ms * 2048);
      float4 xlo = *(const float4*)(rb + (base ^ sw));
      float4 xhi = *(const float4*)(rb + ((base + 16) ^ sw));
      xf[ms] = cvt8(xlo, xhi);
    }
#pragma unroll
    for (int j = 0; j < 3; ++j) {
      half8_t wcur = (j == 0) ? wf0 : ((j == 1) ? wf1 : wf2);
      const int nt = 3 * wv + j;
      if (nt < 8) {  // Q/K: swapped -> D[n][m]
        acc[0][j] = __builtin_amdgcn_mfma_f32_16x16x32_f16(wcur, xf[0], acc[0][j], 0, 0, 0);
        acc[1][j] = __builtin_amdgcn_mfma_f32_16x16x32_f16(wcur, xf[1], acc[1][j], 0, 0, 0);
      } else {       // V: normal -> D[m][n]
        acc[0][j] = __builtin_amdgcn_mfma_f32_16x16x32_f16(xf[0], wcur, acc[0][j], 0, 0, 0);
        acc[1][j] = __builtin_amdgcn_mfma_f32_16x16x32_f16(xf[1], wcur, acc[1][j], 0, 0, 0);
      }
    }
    wf0 = wn0; wf1 = wn1; wf2 = wn2;
    // stage step t+1 (compiler waits on xn's vmcnt before the ds_write)
    *(float4*)(lws + ((t + 1) & 1) * 4096) = xn;
    __syncthreads();
  }
  // final compute: t = 31 from buf[1]
  {
    const char* rb = sbuf + 4096;
    half8_t xf[2];
#pragma unroll
    for (int ms = 0; ms < 2; ++ms) {
      const unsigned base = rA + (unsigned)(ms * 2048);
      float4 xlo = *(const float4*)(rb + (base ^ sw));
      float4 xhi = *(const float4*)(rb + ((base + 16) ^ sw));
      xf[ms] = cvt8(xlo, xhi);
    }
#pragma unroll
    for (int j = 0; j < 3; ++j) {
      half8_t wcur = (j == 0) ? wf0 : ((j == 1) ? wf1 : wf2);
      const int nt = 3 * wv + j;
      if (nt < 8) {
        acc[0][j] = __builtin_amdgcn_mfma_f32_16x16x32_f16(wcur, xf[0], acc[0][j], 0, 0, 0);
        acc[1][j] = __builtin_amdgcn_mfma_f32_16x16x32_f16(wcur, xf[1], acc[1][j], 0, 0, 0);
      } else {
        acc[0][j] = __builtin_amdgcn_mfma_f32_16x16x32_f16(xf[0], wcur, acc[0][j], 0, 0, 0);
        acc[1][j] = __builtin_amdgcn_mfma_f32_16x16x32_f16(xf[1], wcur, acc[1][j], 0, 0, 0);
      }
    }
  }

  // ---- stores ----
  const int b = m0 >> 11;
#pragma unroll
  for (int j = 0; j < 3; ++j) {
    const int nt = 3 * wv + j;
#pragma unroll
    for (int ms = 0; ms < 2; ++ms) {
      half4_t h;
      h[0] = (_Float16)acc[ms][j][0]; h[1] = (_Float16)acc[ms][j][1];
      h[2] = (_Float16)acc[ms][j][2]; h[3] = (_Float16)acc[ms][j][3];
      if (nt < 4) {        // Q: D[n][m]: row m0+ms*16+c, col nt*16+4g+r
        *(half4_t*)(Qh + (size_t)(m0 + ms * 16 + c) * 64 + nt * 16 + 4 * g) = h;
      } else if (nt < 8) { // K
        *(half4_t*)(Kh + (size_t)(m0 + ms * 16 + c) * 64 + (nt - 4) * 16 + 4 * g) = h;
      } else {             // V: D[s][h]: h=(nt-8)*16+c, s=m0+ms*16+4g+r -> Vt[b][h][s]
        const int hh = (nt - 8) * 16 + c;
        const int s0 = (m0 & 2047) + ms * 16 + 4 * g;
        *(half4_t*)(Vt + (size_t)(b * 64 + hh) * 2048 + s0) = h;
      }
    }
  }
}

// ---------------- attn helpers (verbatim r10-r13 passing) ----------------
__device__ __forceinline__ void flash_tile(int q0, int wv, int g, int c,
                                           const _Float16* __restrict__ Qb,
                                           const _Float16* __restrict__ Kb,
                                           const _Float16* __restrict__ Vb,
                                           f32x4 (&acc)[4], float& m2, float& lsum) {
  const f32x4 zero = {0.f, 0.f, 0.f, 0.f};
  const float CS = 0.18033688011112042f;  // 0.125 * log2(e)
  const int q_lane = q0 + c;
  const int nb = ((q0 + 15) >> 6) + 1;

  const _Float16* Qrow = Qb + (size_t)(q0 + c) * 64;
  half8_t qf0 = *(const half8_t*)(Qrow + 8 * g);
  half8_t qf1 = *(const half8_t*)(Qrow + 32 + 8 * g);

  const int addr_u01 = (2 * (g & 1)) * 64 + c * 4;
  const int addr_u23 = (2 * (g & 1) + 1) * 64 + c * 4;
  const bool glo = (g < 2);

  for (int jb = wv; jb < nb; jb += 8) {
    const int k0 = jb * 64;
    f32x4 sacc[4];
#pragma unroll
    for (int kt = 0; kt < 4; ++kt) {
      const _Float16* Krow = Kb + (size_t)(k0 + kt * 16 + c) * 64;
      half8_t kf0 = *(const half8_t*)(Krow + 8 * g);
      half8_t kf1 = *(const half8_t*)(Krow + 32 + 8 * g);
      f32x4 t = zero;
      t = __builtin_amdgcn_mfma_f32_16x16x32_f16(kf0, qf0, t, 0, 0, 0);
      t = __builtin_amdgcn_mfma_f32_16x16x32_f16(kf1, qf1, t, 0, 0, 0);
      sacc[kt] = t;
    }
    half8_t vf0[4], vf1[4];
#pragma unroll
    for (int ht = 0; ht < 4; ++ht) {
      const _Float16* Vrow = Vb + (size_t)(16 * ht + c) * 2048 + k0;
      vf0[ht] = *(const half8_t*)(Vrow + 8 * g);
      vf1[ht] = *(const half8_t*)(Vrow + 32 + 8 * g);
    }
    const bool full = (k0 + 63 <= q0);
    float pv[16];
    float bmax = -3.0e38f;
#pragma unroll
    for (int kt = 0; kt < 4; ++kt) {
#pragma unroll
      for (int r = 0; r < 4; ++r) {
        float sv = sacc[kt][r] * CS;
        if (!full) {
          int kidx = k0 + kt * 16 + 4 * g + r;
          sv = (kidx > q_lane) ? -3.0e38f : sv;
        }
        pv[kt * 4 + r] = sv;
        bmax = fmaxf(bmax, sv);
      }
    }
    bmax = fmaxf(bmax, __shfl_xor(bmax, 16));
    bmax = fmaxf(bmax, __shfl_xor(bmax, 32));
    const float mnew = fmaxf(m2, bmax);
    const float fsc = fexp2(m2 - mnew);
    m2 = mnew;
    float psum = 0.f;
#pragma unroll
    for (int t = 0; t < 16; ++t) {
      pv[t] = fexp2(pv[t] - m2);
      psum += pv[t];
    }
    lsum = lsum * fsc + psum;
#pragma unroll
    for (int ht = 0; ht < 4; ++ht) {
#pragma unroll
      for (int r = 0; r < 4; ++r) acc[ht][r] *= fsc;
    }
    int h2[8];
#pragma unroll
    for (int kt = 0; kt < 4; ++kt) {
#pragma unroll
      for (int bb = 0; bb < 2; ++bb) {
        fp16x2 hv = __builtin_amdgcn_cvt_pkrtz(pv[kt * 4 + 2 * bb],
                                               pv[kt * 4 + 2 * bb + 1]);
        h2[kt * 2 + bb] = __builtin_bit_cast(int, hv);
      }
    }
    half8_t pf0, pf1;
#pragma unroll
    for (int u = 0; u < 4; ++u) {
      const int addr = (u < 2) ? addr_u01 : addr_u23;
#pragma unroll
      for (int h = 0; h < 2; ++h) {
        int r1 = __builtin_amdgcn_ds_bpermute(addr, h2[4 * h + (u & 1)]);
        int r2 = __builtin_amdgcn_ds_bpermute(addr, h2[4 * h + 2 + (u & 1)]);
        half2_t t = __builtin_bit_cast(half2_t, glo ? r1 : r2);
        if (h == 0) { pf0[2 * u] = t[0]; pf0[2 * u + 1] = t[1]; }
        else        { pf1[2 * u] = t[0]; pf1[2 * u + 1] = t[1]; }
      }
    }
#pragma unroll
    for (int ht = 0; ht < 4; ++ht) {
      acc[ht] = __builtin_amdgcn_mfma_f32_16x16x32_f16(vf0[ht], pf0, acc[ht], 0, 0, 0);
      acc[ht] = __builtin_amdgcn_mfma_f32_16x16x32_f16(vf1[ht], pf1, acc[ht], 0, 0, 0);
    }
  }
}

__device__ __forceinline__ void combine_tile(char* shraw, int tid, int wv, int g, int c,
                                             int b, int q0, f32x4 (&acc)[4],
                                             float m2, float lsum,
                                             float* __restrict__ out) {
  float* Mm = (float*)(shraw + 34816);
  float* Ll = (float*)(shraw + 35328);
  lsum += __shfl_xor(lsum, 16);
  lsum += __shfl_xor(lsum, 32);
  Mm[wv * 16 + c] = m2;
  Ll[wv * 16 + c] = lsum;
  float* OmW = (float*)shraw + wv * 1088 + c * 68;
#pragma unroll
  for (int ht = 0; ht < 4; ++ht) {
    *(f32x4*)(OmW + ht * 16 + 4 * g) = acc[ht];
  }
  __syncthreads();
  const int r = tid & 15;
  const int cp = tid >> 4;  // 0..31
  const float* OmF = (const float*)shraw;
  float mf = Mm[r];
#pragma unroll
  for (int i = 1; i < 8; ++i) mf = fmaxf(mf, Mm[i * 16 + r]);
  float lf = 0.f, o0 = 0.f, o1 = 0.f;
#pragma unroll
  for (int i = 0; i < 8; ++i) {
    float sc = fexp2(Mm[i * 16 + r] - mf);
    lf += Ll[i * 16 + r] * sc;
    const float* p = OmF + i * 1088 + r * 68 + 2 * cp;
    o0 += p[0] * sc;
    o1 += p[1] * sc;
  }
  const float inv = 1.0f / lf;
  float2 o;
  o.x = o0 * inv;
  o.y = o1 * inv;
  *(float2*)(out + (size_t)(b * 2048 + q0 + r) * 64 + 2 * cp) = o;
}

// ---------------- kernel 3: causal flash attention, paired q-tiles ----------------
__global__ __launch_bounds__(512) void attn_kernel(const _Float16* __restrict__ Qh,
                                                   const _Float16* __restrict__ Kh,
                                                   const _Float16* __restrict__ Vt,
                                                   float* __restrict__ out) {
  __shared__ __align__(16) char shraw[35840];

  const int tid = threadIdx.x;
  const int lane = tid & 63;
  const int wv = tid >> 6;       // 0..7
  const int g = lane >> 4;
  const int c = lane & 15;
  const int pr = blockIdx.x & 63;   // pair index 0..63
  const int b = blockIdx.x >> 6;
  const int q0A = pr * 16;              // small tile
  const int q0B = (127 - pr) * 16;      // large tile

  const _Float16* Qb = Qh + (size_t)b * 2048 * 64;
  const _Float16* Kb = Kh + (size_t)b * 2048 * 64;
  const _Float16* Vb = Vt + (size_t)b * 64 * 2048;

  const f32x4 zero = {0.f, 0.f, 0.f, 0.f};
  f32x4 accA[4], accB[4];
#pragma unroll
  for (int t = 0; t < 4; ++t) { accA[t] = zero; accB[t] = zero; }
  float mA = -3.0e38f, lA = 0.f;
  float mB = -3.0e38f, lB = 0.f;

  flash_tile(q0A, wv, g, c, Qb, Kb, Vb, accA, mA, lA);
  flash_tile(q0B, wv, g, c, Qb, Kb, Vb, accB, mB, lB);

  combine_tile(shraw, tid, wv, g, c, b, q0A, accA, mA, lA, out);
  __syncthreads();  // A's Om reads done before B overwrites
  combine_tile(shraw, tid, wv, g, c, b, q0B, accB, mB, lB, out);
}

extern "C" void kernel_launch(void* const* d_in, const int* in_sizes, int n_in,
                              void* d_out, int out_size, void* d_ws, size_t ws_size,
                              hipStream_t stream) {
  const float* x  = (const float*)d_in[0];
  const float* Wq = (const float*)d_in[1];
  const float* Wk = (const float*)d_in[2];
  const float* Wv = (const float*)d_in[3];
  char* ws = (char*)d_ws;
  _Float16* Wt = (_Float16*)(ws);                // 192*1024*2      = 393216 B
  _Float16* Qh = (_Float16*)(ws + 393216);       // 16384*64*2      = 2097152 B
  _Float16* Kh = (_Float16*)(ws + 2490368);      // 16384*64*2
  _Float16* Vt = (_Float16*)(ws + 4587520);      // 8*64*2048*2
  float* out = (float*)d_out;

  wt_kernel<<<dim3(768), dim3(256), 0, stream>>>(Wq, Wk, Wv, Wt);
  proj_kernel<<<dim3(512), dim3(256), 0, stream>>>(x, Wt, Qh, Kh, Vt);
  attn_kernel<<<dim3(512), dim3(512), 0, stream>>>(Qh, Kh, Vt, out);
}